// Round 11
// baseline (63.952 us; speedup 1.0000x reference)
//
#include <hip/hip_runtime.h>
#include <math.h>

constexpr int M_TOK = 8;
constexpr int N_OUT = 8192;
constexpr int K_IN  = 8192;
constexpr int KG    = 64;   // K / G, G = 128
constexpr int R_N   = 4;    // output rows per wave
constexpr int NPH   = 32;   // stagger phases (256-k granularity)

typedef int   i32x4 __attribute__((ext_vector_type(4)));
typedef float f32x4 __attribute__((ext_vector_type(4)));

// ---------------- Kernel 1: per-token symmetric int8 fake-quant ----------------
__global__ __launch_bounds__(1024) void act_quant_kernel(const float* __restrict__ x,
                                                         float* __restrict__ xq) {
    const int row = blockIdx.x;
    const f32x4* xr = reinterpret_cast<const f32x4*>(x + (size_t)row * K_IN);
    f32x4* oq = reinterpret_cast<f32x4*>(xq + (size_t)row * K_IN);
    const int tid = threadIdx.x;

    f32x4 v0 = xr[tid * 2];
    f32x4 v1 = xr[tid * 2 + 1];

    float m = fmaxf(
        fmaxf(fmaxf(fabsf(v0.x), fabsf(v0.y)), fmaxf(fabsf(v0.z), fabsf(v0.w))),
        fmaxf(fmaxf(fabsf(v1.x), fabsf(v1.y)), fmaxf(fabsf(v1.z), fabsf(v1.w))));

    #pragma unroll
    for (int off = 32; off; off >>= 1) m = fmaxf(m, __shfl_xor(m, off));

    __shared__ float smax[16];
    if ((tid & 63) == 0) smax[tid >> 6] = m;
    __syncthreads();
    float mm = smax[0];
    #pragma unroll
    for (int i = 1; i < 16; ++i) mm = fmaxf(mm, smax[i]);

    const float s = fmaxf(mm / 127.0f, 1e-8f);

    auto quant = [&](float v) -> float {
        float q = rintf(v / s);              // numpy round = half-to-even
        q = fminf(fmaxf(q, -127.0f), 127.0f);
        return q * s;
    };

    f32x4 o0, o1;
    o0.x = quant(v0.x); o0.y = quant(v0.y); o0.z = quant(v0.z); o0.w = quant(v0.w);
    o1.x = quant(v1.x); o1.y = quant(v1.y); o1.z = quant(v1.z); o1.w = quant(v1.w);
    oq[tid * 2]     = o0;
    oq[tid * 2 + 1] = o1;
}

// ---------------- Kernel 2: staggered + burst-grouped dequant-GEMM ----------------
// r9 skeleton (barrier-free, per-wave k-phase stagger: 68.5->59.6 us) with the
// k-loop unrolled 4x and weight issue GROUPED PER ROW: 16 back-to-back loads
// = 4 KiB contiguous per row per iteration (4x longer DRAM bursts, same bytes).
// Weight regs are consumed within the iteration (NOT a cross-iter rotate - r3).
// Ledger: LDS-DMA dbuf REGRESSED w/ stagger (r10); nt REGRESSED (r8); VGPR
// prefetch-rotate REGRESSED (r3); split-K/xq-LDS/fusion NULL (r4-r6).
__global__ __launch_bounds__(256) void qlin_kernel(const float* __restrict__ xq,
                                                   const int* __restrict__ qw,
                                                   const float* __restrict__ scales,
                                                   const float* __restrict__ bias,
                                                   float* __restrict__ out) {
    const int wave = blockIdx.x * 4 + (threadIdx.x >> 6);
    const int lane = threadIdx.x & 63;
    const int n0 = wave * R_N;
    const int lk = lane * 4;
    const int phase = (wave & (NPH - 1)) * 256;   // per-wave k start

    float acc[R_N][M_TOK];
    #pragma unroll
    for (int r = 0; r < R_N; ++r)
        #pragma unroll
        for (int m = 0; m < M_TOK; ++m) acc[r][m] = 0.0f;

    const int* wr0 = qw + (size_t)(n0 + 0) * K_IN;
    const int* wr1 = qw + (size_t)(n0 + 1) * K_IN;
    const int* wr2 = qw + (size_t)(n0 + 2) * K_IN;
    const int* wr3 = qw + (size_t)(n0 + 3) * K_IN;
    const float* sp0 = scales + (size_t)(n0 + 0) * KG;
    const float* sp1 = scales + (size_t)(n0 + 1) * KG;
    const float* sp2 = scales + (size_t)(n0 + 2) * KG;
    const float* sp3 = scales + (size_t)(n0 + 3) * KG;

    // one 256-k chunk of compute for all 4 rows, weights already in regs
    auto do_chunk = [&](int kk, const i32x4& c0, const i32x4& c1,
                        const i32x4& c2, const i32x4& c3) {
        const int g = kk >> 7;
        f32x4 xv[M_TOK];
        #pragma unroll
        for (int m = 0; m < M_TOK; ++m)
            xv[m] = *reinterpret_cast<const f32x4*>(xq + (size_t)m * K_IN + kk);

        {
            const float sc = sp0[g];
            const float w0 = (float)c0.x * sc, w1 = (float)c0.y * sc,
                        w2 = (float)c0.z * sc, w3 = (float)c0.w * sc;
            #pragma unroll
            for (int m = 0; m < M_TOK; ++m) {
                float a = acc[0][m];
                a = fmaf(w0, xv[m].x, a); a = fmaf(w1, xv[m].y, a);
                a = fmaf(w2, xv[m].z, a); a = fmaf(w3, xv[m].w, a);
                acc[0][m] = a;
            }
        }
        {
            const float sc = sp1[g];
            const float w0 = (float)c1.x * sc, w1 = (float)c1.y * sc,
                        w2 = (float)c1.z * sc, w3 = (float)c1.w * sc;
            #pragma unroll
            for (int m = 0; m < M_TOK; ++m) {
                float a = acc[1][m];
                a = fmaf(w0, xv[m].x, a); a = fmaf(w1, xv[m].y, a);
                a = fmaf(w2, xv[m].z, a); a = fmaf(w3, xv[m].w, a);
                acc[1][m] = a;
            }
        }
        {
            const float sc = sp2[g];
            const float w0 = (float)c2.x * sc, w1 = (float)c2.y * sc,
                        w2 = (float)c2.z * sc, w3 = (float)c2.w * sc;
            #pragma unroll
            for (int m = 0; m < M_TOK; ++m) {
                float a = acc[2][m];
                a = fmaf(w0, xv[m].x, a); a = fmaf(w1, xv[m].y, a);
                a = fmaf(w2, xv[m].z, a); a = fmaf(w3, xv[m].w, a);
                acc[2][m] = a;
            }
        }
        {
            const float sc = sp3[g];
            const float w0 = (float)c3.x * sc, w1 = (float)c3.y * sc,
                        w2 = (float)c3.z * sc, w3 = (float)c3.w * sc;
            #pragma unroll
            for (int m = 0; m < M_TOK; ++m) {
                float a = acc[3][m];
                a = fmaf(w0, xv[m].x, a); a = fmaf(w1, xv[m].y, a);
                a = fmaf(w2, xv[m].z, a); a = fmaf(w3, xv[m].w, a);
                acc[3][m] = a;
            }
        }
    };

    for (int tt = 0; tt < 8; ++tt) {
        const int base = phase + tt * 1024;
        const int ka = ((base)        & (K_IN - 1)) + lk;
        const int kb = ((base + 256)  & (K_IN - 1)) + lk;
        const int kc = ((base + 512)  & (K_IN - 1)) + lk;
        const int kd = ((base + 768)  & (K_IN - 1)) + lk;

        // grouped weight issue: 4 consecutive 1-KiB chunks per row,
        // row-major order -> 4 KiB contiguous bursts per row stream
        const i32x4 a0 = *reinterpret_cast<const i32x4*>(wr0 + ka);
        const i32x4 a1 = *reinterpret_cast<const i32x4*>(wr0 + kb);
        const i32x4 a2 = *reinterpret_cast<const i32x4*>(wr0 + kc);
        const i32x4 a3 = *reinterpret_cast<const i32x4*>(wr0 + kd);
        const i32x4 b0 = *reinterpret_cast<const i32x4*>(wr1 + ka);
        const i32x4 b1 = *reinterpret_cast<const i32x4*>(wr1 + kb);
        const i32x4 b2 = *reinterpret_cast<const i32x4*>(wr1 + kc);
        const i32x4 b3 = *reinterpret_cast<const i32x4*>(wr1 + kd);
        const i32x4 c0 = *reinterpret_cast<const i32x4*>(wr2 + ka);
        const i32x4 c1 = *reinterpret_cast<const i32x4*>(wr2 + kb);
        const i32x4 c2 = *reinterpret_cast<const i32x4*>(wr2 + kc);
        const i32x4 c3 = *reinterpret_cast<const i32x4*>(wr2 + kd);
        const i32x4 d0 = *reinterpret_cast<const i32x4*>(wr3 + ka);
        const i32x4 d1 = *reinterpret_cast<const i32x4*>(wr3 + kb);
        const i32x4 d2 = *reinterpret_cast<const i32x4*>(wr3 + kc);
        const i32x4 d3 = *reinterpret_cast<const i32x4*>(wr3 + kd);

        do_chunk(ka, a0, b0, c0, d0);
        do_chunk(kb, a1, b1, c1, d1);
        do_chunk(kc, a2, b2, c2, d2);
        do_chunk(kd, a3, b3, c3, d3);
    }

    // full butterfly reduce -> every lane holds each (r,m) total
    #pragma unroll
    for (int r = 0; r < R_N; ++r)
        #pragma unroll
        for (int m = 0; m < M_TOK; ++m) {
            float v = acc[r][m];
            #pragma unroll
            for (int off = 32; off; off >>= 1) v += __shfl_xor(v, off);
            acc[r][m] = v;
        }

    // lane (r*8 + m) writes out[m][n0+r]
    if (lane < R_N * M_TOK) {
        const int rsel = lane >> 3;
        const int msel = lane & 7;
        float myv = 0.0f;
        #pragma unroll
        for (int r = 0; r < R_N; ++r)
            #pragma unroll
            for (int m = 0; m < M_TOK; ++m)
                if (r == rsel && m == msel) myv = acc[r][m];
        out[(size_t)msel * N_OUT + n0 + rsel] = myv + bias[n0 + rsel];
    }
}

extern "C" void kernel_launch(void* const* d_in, const int* in_sizes, int n_in,
                              void* d_out, int out_size, void* d_ws, size_t ws_size,
                              hipStream_t stream) {
    const float* x      = (const float*)d_in[0];
    const int*   qw     = (const int*)d_in[1];
    const float* scales = (const float*)d_in[2];
    const float* bias   = (const float*)d_in[3];
    float* out = (float*)d_out;
    float* xq  = (float*)d_ws;  // M*K floats = 256 KiB scratch

    act_quant_kernel<<<M_TOK, 1024, 0, stream>>>(x, xq);

    const int waves  = N_OUT / R_N;        // 2048
    const int blocks = waves / 4;          // 512 blocks x 256 threads
    qlin_kernel<<<blocks, 256, 0, stream>>>(xq, qw, scales, bias, out);
}

// Round 12
// 56.825 us; speedup vs baseline: 1.1254x; 1.1254x over previous
//
#include <hip/hip_runtime.h>
#include <math.h>

constexpr int M_TOK = 8;
constexpr int N_OUT = 8192;
constexpr int K_IN  = 8192;
constexpr int KG    = 64;   // K / G, G = 128
constexpr int R_N   = 4;    // output rows per wave

typedef int   i32x4 __attribute__((ext_vector_type(4)));
typedef float f32x4 __attribute__((ext_vector_type(4)));

// ---------------- Kernel 1: per-token symmetric int8 fake-quant ----------------
__global__ __launch_bounds__(1024) void act_quant_kernel(const float* __restrict__ x,
                                                         float* __restrict__ xq) {
    const int row = blockIdx.x;
    const f32x4* xr = reinterpret_cast<const f32x4*>(x + (size_t)row * K_IN);
    f32x4* oq = reinterpret_cast<f32x4*>(xq + (size_t)row * K_IN);
    const int tid = threadIdx.x;

    f32x4 v0 = xr[tid * 2];
    f32x4 v1 = xr[tid * 2 + 1];

    float m = fmaxf(
        fmaxf(fmaxf(fabsf(v0.x), fabsf(v0.y)), fmaxf(fabsf(v0.z), fabsf(v0.w))),
        fmaxf(fmaxf(fabsf(v1.x), fabsf(v1.y)), fmaxf(fabsf(v1.z), fabsf(v1.w))));

    #pragma unroll
    for (int off = 32; off; off >>= 1) m = fmaxf(m, __shfl_xor(m, off));

    __shared__ float smax[16];
    if ((tid & 63) == 0) smax[tid >> 6] = m;
    __syncthreads();
    float mm = smax[0];
    #pragma unroll
    for (int i = 1; i < 16; ++i) mm = fmaxf(mm, smax[i]);

    const float s = fmaxf(mm / 127.0f, 1e-8f);

    auto quant = [&](float v) -> float {
        float q = rintf(v / s);              // numpy round = half-to-even
        q = fminf(fmaxf(q, -127.0f), 127.0f);
        return q * s;
    };

    f32x4 o0, o1;
    o0.x = quant(v0.x); o0.y = quant(v0.y); o0.z = quant(v0.z); o0.w = quant(v0.w);
    o1.x = quant(v1.x); o1.y = quant(v1.y); o1.z = quant(v1.z); o1.w = quant(v1.w);
    oq[tid * 2]     = o0;
    oq[tid * 2 + 1] = o1;
}

// ---------------- Kernel 2: dequant + skinny GEMM, fine-staggered k ----------------
// r9 skeleton (barrier-free; per-wave k-phase stagger gave 68.5->59.6 us).
// Single change vs r9: stagger refined from 32 phase classes @1 KiB (64 waves
// exactly in-phase per class) to 256 classes @128 B (8 waves per class).
// Per-lane k wraps via & 8191 (k stays multiple of 4; g computed per-lane).
// Ledger: burst-group REGRESSED (r11); LDS-DMA dbuf w/ stagger REGRESSED (r10);
// nt REGRESSED (r8); VGPR prefetch-rotate REGRESSED (r3); split-K (r4),
// xq-LDS (r5), fusion (r6), global_load_lds (r7) NULL.
__global__ __launch_bounds__(256) void qlin_kernel(const float* __restrict__ xq,
                                                   const int* __restrict__ qw,
                                                   const float* __restrict__ scales,
                                                   const float* __restrict__ bias,
                                                   float* __restrict__ out) {
    const int wave = blockIdx.x * 4 + (threadIdx.x >> 6);
    const int lane = threadIdx.x & 63;
    const int n0 = wave * R_N;
    const int lk = lane * 4;
    const int phase = (wave & 255) * 32;   // 256 classes, 128 B granularity

    float acc[R_N][M_TOK];
    #pragma unroll
    for (int r = 0; r < R_N; ++r)
        #pragma unroll
        for (int m = 0; m < M_TOK; ++m) acc[r][m] = 0.0f;

    for (int t = 0; t < 32; ++t) {
        const int k = (phase + t * 256 + lk) & (K_IN - 1);  // mult of 4; no intra-vec wrap
        const int g = k >> 7;  // per-lane group index; 4 consecutive k share one group

        f32x4 xv[M_TOK];
        #pragma unroll
        for (int m = 0; m < M_TOK; ++m)
            xv[m] = *reinterpret_cast<const f32x4*>(xq + (size_t)m * K_IN + k);

        #pragma unroll
        for (int r = 0; r < R_N; ++r) {
            const i32x4 c =
                *reinterpret_cast<const i32x4*>(qw + (size_t)(n0 + r) * K_IN + k);
            const float sc = scales[(size_t)(n0 + r) * KG + g];
            const float w0 = (float)c.x * sc;
            const float w1 = (float)c.y * sc;
            const float w2 = (float)c.z * sc;
            const float w3 = (float)c.w * sc;
            #pragma unroll
            for (int m = 0; m < M_TOK; ++m) {
                float a = acc[r][m];
                a = fmaf(w0, xv[m].x, a);
                a = fmaf(w1, xv[m].y, a);
                a = fmaf(w2, xv[m].z, a);
                a = fmaf(w3, xv[m].w, a);
                acc[r][m] = a;
            }
        }
    }

    // full butterfly reduce -> every lane holds each (r,m) total
    #pragma unroll
    for (int r = 0; r < R_N; ++r)
        #pragma unroll
        for (int m = 0; m < M_TOK; ++m) {
            float v = acc[r][m];
            #pragma unroll
            for (int off = 32; off; off >>= 1) v += __shfl_xor(v, off);
            acc[r][m] = v;
        }

    // lane (r*8 + m) writes out[m][n0+r]
    if (lane < R_N * M_TOK) {
        const int rsel = lane >> 3;
        const int msel = lane & 7;
        float myv = 0.0f;
        #pragma unroll
        for (int r = 0; r < R_N; ++r)
            #pragma unroll
            for (int m = 0; m < M_TOK; ++m)
                if (r == rsel && m == msel) myv = acc[r][m];
        out[(size_t)msel * N_OUT + n0 + rsel] = myv + bias[n0 + rsel];
    }
}

extern "C" void kernel_launch(void* const* d_in, const int* in_sizes, int n_in,
                              void* d_out, int out_size, void* d_ws, size_t ws_size,
                              hipStream_t stream) {
    const float* x      = (const float*)d_in[0];
    const int*   qw     = (const int*)d_in[1];
    const float* scales = (const float*)d_in[2];
    const float* bias   = (const float*)d_in[3];
    float* out = (float*)d_out;
    float* xq  = (float*)d_ws;  // M*K floats = 256 KiB scratch

    act_quant_kernel<<<M_TOK, 1024, 0, stream>>>(x, xq);

    const int waves  = N_OUT / R_N;        // 2048
    const int blocks = waves / 4;          // 512 blocks x 256 threads
    qlin_kernel<<<blocks, 256, 0, stream>>>(xq, qw, scales, bias, out);
}